// Round 1
// baseline (114.559 us; speedup 1.0000x reference)
//
#include <hip/hip_runtime.h>
#include <hip/hip_bf16.h>
#include <math.h>
#include <stdint.h>

#define BB 4
#define SS 2048
#define DD 768
#define NN 1536          // 2*DD: [Q | K]
#define MM (BB*SS)       // 8192

typedef __attribute__((ext_vector_type(4))) float  f32x4;
typedef __attribute__((ext_vector_type(8))) __bf16 bf16x8;
typedef __attribute__((ext_vector_type(4))) __bf16 bf16x4;

#define AS1 __attribute__((address_space(1)))
#define AS3 __attribute__((address_space(3)))

// ---------------- K1: LayerNorm (fp32 in, bf16 out) ----------------
__global__ __launch_bounds__(192) void ln_kernel(const float* __restrict__ x,
        const float* __restrict__ lw, const float* __restrict__ lb,
        __bf16* __restrict__ h) {
    const int row = blockIdx.x;          // 0..MM-1
    const int t = threadIdx.x;           // 0..191, 4 elems each
    const float* xr = x + (size_t)row * DD;
    f32x4 v = *(const f32x4*)(xr + t * 4);
    float s  = v[0] + v[1] + v[2] + v[3];
    float ss = v[0]*v[0] + v[1]*v[1] + v[2]*v[2] + v[3]*v[3];
#pragma unroll
    for (int o = 1; o < 64; o <<= 1) { s += __shfl_xor(s, o); ss += __shfl_xor(ss, o); }
    __shared__ float smS[3], smQ[3];
    if ((t & 63) == 0) { smS[t >> 6] = s; smQ[t >> 6] = ss; }
    __syncthreads();
    float tS = smS[0] + smS[1] + smS[2];
    float tQ = smQ[0] + smQ[1] + smQ[2];
    float mu  = tS * (1.0f / DD);
    float var = tQ * (1.0f / DD) - mu * mu;
    float rstd = 1.0f / sqrtf(var + 1e-12f);
    f32x4 wv = *(const f32x4*)(lw + t * 4);
    f32x4 bv = *(const f32x4*)(lb + t * 4);
    bf16x4 o;
#pragma unroll
    for (int c = 0; c < 4; c++) {
        float y = (v[c] - mu) * rstd * wv[c] + bv[c];
        o[c] = (__bf16)y;
    }
    *(bf16x4*)(h + (size_t)row * DD + t * 4) = o;
}

// ---------------- K2: W=[wq|wk] -> Wt[n][k] bf16 (transposed) ----------------
__global__ __launch_bounds__(256) void wt_kernel(const float* __restrict__ wq,
        const float* __restrict__ wk, __bf16* __restrict__ Wt) {
    __shared__ float tile[64][65];
    const int n0 = blockIdx.x * 64;      // 0..1472
    const int k0 = blockIdx.y * 64;      // 0..704
    const float* src = (n0 < DD) ? wq : wk;
    const int nc = (n0 < DD) ? n0 : (n0 - DD);
    for (int e = threadIdx.x; e < 64 * 64; e += 256) {
        int r = e >> 6, c = e & 63;      // r: k-offset, c: n-offset
        tile[r][c] = src[(size_t)(k0 + r) * DD + nc + c];
    }
    __syncthreads();
    for (int e = threadIdx.x; e < 64 * 64; e += 256) {
        int r = e >> 6, c = e & 63;      // r: n-offset, c: k-offset
        Wt[(size_t)(n0 + r) * DD + k0 + c] = (__bf16)tile[c][r];
    }
}

// ---------------- K3: GEMM  C[M,NN] = h[M,DD] @ W[DD,NN] + bias ----------------
// 128x128 tile, 4 waves (2x2 of 64x64), BK=32, mfma_f32_16x16x32_bf16,
// global_load_lds width 16, Bt stored transposed (Wt[n][k]).
__global__ __launch_bounds__(256) void gemm_kernel(const __bf16* __restrict__ A,
        const __bf16* __restrict__ Bt,
        const float* __restrict__ bq, const float* __restrict__ bk,
        float* __restrict__ C) {
    __shared__ __attribute__((aligned(16))) __bf16 As[128][32];
    __shared__ __attribute__((aligned(16))) __bf16 Bs[128][32];
    const int m0 = blockIdx.x * 128;
    const int n0 = blockIdx.y * 128;
    const int t = threadIdx.x;
    const int wave = t >> 6, lane = t & 63;
    const int wr = wave >> 1, wc = wave & 1;
    f32x4 acc[4][4] = {};

    char* asb = (char*)&As[0][0];
    char* bsb = (char*)&Bs[0][0];
    const int c0  = wave * 64 + lane;        // chunk id (16B chunks), issue 0
    const int rA0 = c0 >> 2;                 // tile row (4 chunks per 64B row)
    const int cA0 = (c0 & 3) << 3;           // k-element offset within row

    for (int k0 = 0; k0 < DD; k0 += 32) {
        const __bf16* ga0 = A  + (size_t)(m0 + rA0) * DD + k0 + cA0;
        const __bf16* ga1 = ga0 + (size_t)64 * DD;
        const __bf16* gb0 = Bt + (size_t)(n0 + rA0) * DD + k0 + cA0;
        const __bf16* gb1 = gb0 + (size_t)64 * DD;
        __builtin_amdgcn_global_load_lds((const AS1 void*)(ga0), (AS3 void*)(asb + wave * 1024),        16, 0, 0);
        __builtin_amdgcn_global_load_lds((const AS1 void*)(ga1), (AS3 void*)(asb + 4096 + wave * 1024), 16, 0, 0);
        __builtin_amdgcn_global_load_lds((const AS1 void*)(gb0), (AS3 void*)(bsb + wave * 1024),        16, 0, 0);
        __builtin_amdgcn_global_load_lds((const AS1 void*)(gb1), (AS3 void*)(bsb + 4096 + wave * 1024), 16, 0, 0);
        __syncthreads();
        const int r = lane & 15, ko = (lane >> 4) << 3;
        bf16x8 af[4], bvf[4];
#pragma unroll
        for (int i = 0; i < 4; i++) af[i]  = *(const bf16x8*)&As[wr * 64 + i * 16 + r][ko];
#pragma unroll
        for (int j = 0; j < 4; j++) bvf[j] = *(const bf16x8*)&Bs[wc * 64 + j * 16 + r][ko];
#pragma unroll
        for (int i = 0; i < 4; i++)
#pragma unroll
            for (int j = 0; j < 4; j++)
                acc[i][j] = __builtin_amdgcn_mfma_f32_16x16x32_bf16(af[i], bvf[j], acc[i][j], 0, 0, 0);
        __syncthreads();
    }
    // epilogue: C[row,col], col=lane&15, row=(lane>>4)*4+rr  (m89-verified layout)
#pragma unroll
    for (int i = 0; i < 4; i++) {
        const int mm = m0 + wr * 64 + i * 16 + (lane >> 4) * 4;
#pragma unroll
        for (int j = 0; j < 4; j++) {
            const int nn = n0 + wc * 64 + j * 16 + (lane & 15);
            const float bias = (nn < DD) ? bq[nn] : bk[nn - DD];
#pragma unroll
            for (int rr = 0; rr < 4; rr++)
                C[(size_t)(mm + rr) * NN + nn] = acc[i][j][rr] + bias;
        }
    }
}

// ---------------- K4: band dots + 2-way softmax ----------------
__global__ __launch_bounds__(256) void band_kernel(const float* __restrict__ QK,
        const int* __restrict__ att, float* __restrict__ pu, float* __restrict__ pd) {
    const int idx  = blockIdx.x * 4 + (threadIdx.x >> 6);   // row 0..MM-1
    const int lane = threadIdx.x & 63;
    const int b = idx >> 11;        // /SS
    const int s = idx & 2047;       // %SS
    const float* q = QK + (size_t)idx * NN;                 // Q in cols [0,DD)
    float qv[12];
#pragma unroll
    for (int m = 0; m < 12; m++) qv[m] = q[lane + 64 * m];
    float du = 0.f, dn = 0.f;
    if (s < SS - 1) {
        const float* kk = QK + (size_t)(idx + 1) * NN + DD;
#pragma unroll
        for (int m = 0; m < 12; m++) du += qv[m] * kk[lane + 64 * m];
    }
    if (s > 0) {
        const float* kk = QK + (size_t)(idx - 1) * NN + DD;
#pragma unroll
        for (int m = 0; m < 12; m++) dn += qv[m] * kk[lane + 64 * m];
    }
#pragma unroll
    for (int o = 1; o < 64; o <<= 1) { du += __shfl_xor(du, o); dn += __shfl_xor(dn, o); }
    if (lane == 0) {
        const float eu = du * (1.0f / DD), ed = dn * (1.0f / DD);
        const bool au = (s < SS - 1) && ((att[((size_t)b * SS + s) * SS + (s + 1)] & 1) != 0);
        const bool ad = (s > 0)      && ((att[((size_t)b * SS + s) * SS + (s - 1)] & 1) != 0);
        float puv = 0.f, pdv = 0.f;
        if (au || ad) {
            float mx = au ? eu : ed;
            if (au && ad) mx = fmaxf(eu, ed);
            const float zu = au ? expf(eu - mx) : 0.f;
            const float zd = ad ? expf(ed - mx) : 0.f;
            const float iz = 1.f / (zu + zd);
            puv = zu * iz; pdv = zd * iz;
        }
        pu[idx] = puv; pd[idx] = pdv;
    }
}

// ---------------- K5: per-batch band n, log, double prefix scan ----------------
__global__ __launch_bounds__(256) void scan_kernel(const float* __restrict__ pu,
        const float* __restrict__ pd, const float* __restrict__ prior,
        float* __restrict__ nb, double* __restrict__ P) {
    const int b = blockIdx.x;
    const int t = threadIdx.x;
    double L[8];
    double mysum = 0.0;
#pragma unroll
    for (int e = 0; e < 8; e++) {
        const int s = t * 8 + e;
        double Lv = 0.0;
        float nbv = 0.f;
        if (s < SS - 1) {
            const float a = pu[b * SS + s];
            const float c = pd[b * SS + s + 1];
            nbv = sqrtf(a * c + 1e-9f);
            const float pr = prior[(size_t)b * SS * SS + (size_t)s * SS + s + 1];
            const float nsup = pr + (1.f - pr) * nbv;
            Lv = log((double)nsup + 1e-9);
        }
        nb[b * SS + s] = nbv;
        L[e] = Lv; mysum += Lv;
    }
    __shared__ double warr[256];
    warr[t] = mysum;
    __syncthreads();
    for (int o = 1; o < 256; o <<= 1) {
        double v = 0.0;
        if (t >= o) v = warr[t - o];
        __syncthreads();
        if (t >= o) warr[t] += v;
        __syncthreads();
    }
    double run = warr[t] - mysum;    // exclusive prefix across threads
#pragma unroll
    for (int e = 0; e < 8; e++) {
        P[(size_t)b * SS + t * 8 + e] = run;
        run += L[e];
    }
}

// ---------------- K6: fused elementwise output (g and n) ----------------
__global__ __launch_bounds__(256) void out_kernel(const float* __restrict__ prior,
        const float* __restrict__ nb, const double* __restrict__ P,
        float* __restrict__ gout, float* __restrict__ nout) {
    const size_t f = (size_t)blockIdx.x * 256 + threadIdx.x;   // float4 index
    const int b = (int)(f >> 20);            // SS*SS/4 = 2^20
    const size_t r = f & 1048575;
    const int i  = (int)(r >> 9);            // SS/4 = 512 float4 per row
    const int k4 = (int)(r & 511) * 4;
    const f32x4 pv = *(const f32x4*)(prior + (f << 2));
    const double Pi = P[(size_t)b * SS + i];
    f32x4 nres, gres;
#pragma unroll
    for (int c = 0; c < 4; c++) {
        const int k = k4 + c;
        const float pr = pv[c];
        float v = 3.16227766016838e-5f;      // sqrt(1e-9)
        if (k == i + 1)      v = nb[b * SS + i];
        else if (k == i - 1) v = nb[b * SS + k];
        const float nval = pr + (1.f - pr) * v;
        nres[c] = nval;
        float g;
        if (k == i) {
            g = nval;                        // diagonal: diag_part = n[i,i]
        } else {
            const double Pk = P[(size_t)b * SS + k];
            const double dd = (k > i) ? (Pk - Pi) : (Pi - Pk);
            g = expf((float)dd) + 1e-9f;
        }
        gres[c] = g;
    }
    *(f32x4*)(gout + (f << 2)) = gres;
    *(f32x4*)(nout + (f << 2)) = nres;
}

extern "C" void kernel_launch(void* const* d_in, const int* in_sizes, int n_in,
                              void* d_out, int out_size, void* d_ws, size_t ws_size,
                              hipStream_t stream) {
    const float* hs    = (const float*)d_in[0];
    const int*   att   = (const int*)d_in[1];
    const float* prior = (const float*)d_in[2];
    const float* ln_w  = (const float*)d_in[3];
    const float* ln_b  = (const float*)d_in[4];
    const float* wq    = (const float*)d_in[5];
    const float* bq    = (const float*)d_in[6];
    const float* wk    = (const float*)d_in[7];
    const float* bk    = (const float*)d_in[8];

    float* gout = (float*)d_out;                       // g first (return order)
    float* nout = gout + (size_t)BB * SS * SS;

    char* ws = (char*)d_ws;
    __bf16* h   = (__bf16*)(ws);                       // 12,582,912 B
    __bf16* Wt  = (__bf16*)(ws + 12582912);            //  2,359,296 B
    float*  QK  = (float*)(ws + 14942208);             // 50,331,648 B
    float*  pu  = (float*)(ws + 65273856);             //     32,768 B
    float*  pd  = (float*)(ws + 65306624);             //     32,768 B
    float*  nb  = (float*)(ws + 65339392);             //     32,768 B
    double* P   = (double*)(ws + 65372160);            //     65,536 B

    ln_kernel<<<dim3(MM), dim3(192), 0, stream>>>(hs, ln_w, ln_b, h);
    wt_kernel<<<dim3(NN / 64, DD / 64), dim3(256), 0, stream>>>(wq, wk, Wt);
    gemm_kernel<<<dim3(MM / 128, NN / 128), dim3(256), 0, stream>>>(h, Wt, bq, bk, QK);
    band_kernel<<<dim3(MM / 4), dim3(256), 0, stream>>>(QK, att, pu, pd);
    scan_kernel<<<dim3(BB), dim3(256), 0, stream>>>(pu, pd, prior, nb, P);
    out_kernel<<<dim3((BB * SS * SS / 4) / 256), dim3(256), 0, stream>>>(prior, nb, P, gout, nout);
}

// Round 2
// 110.795 us; speedup vs baseline: 1.0340x; 1.0340x over previous
//
#include <hip/hip_runtime.h>
#include <hip/hip_bf16.h>
#include <math.h>
#include <stdint.h>

#define BB 4
#define SS 2048
#define DD 768
#define MM (BB*SS)       // 8192

typedef __attribute__((ext_vector_type(4))) float  f32x4;
typedef __attribute__((ext_vector_type(8))) __bf16 bf16x8;
typedef __attribute__((ext_vector_type(4))) __bf16 bf16x4;

#define AS1 __attribute__((address_space(1)))
#define AS3 __attribute__((address_space(3)))

// ---------------- K0: convert Wq, Wk fp32 -> bf16 ----------------
__global__ __launch_bounds__(256) void wcvt_kernel(const float* __restrict__ wq,
        const float* __restrict__ wk, __bf16* __restrict__ Wqb, __bf16* __restrict__ Wkb) {
    const int bid = blockIdx.x;
    const float* src; __bf16* dst; int off;
    if (bid < 576) { src = wq; dst = Wqb; off = bid; }
    else           { src = wk; dst = Wkb; off = bid - 576; }
    const size_t e = ((size_t)off * 256 + threadIdx.x) * 4;
    f32x4 v = *(const f32x4*)(src + e);
    bf16x4 o;
#pragma unroll
    for (int c = 0; c < 4; c++) o[c] = (__bf16)v[c];
    *(bf16x4*)(dst + e) = o;
}

// ---------------- K1: u = Wq@bk, v = Wk@bq, cb = bq.bk ----------------
__global__ __launch_bounds__(256) void uvcb_kernel(const float* __restrict__ wq,
        const float* __restrict__ wk, const float* __restrict__ bq,
        const float* __restrict__ bk, float* __restrict__ u, float* __restrict__ v,
        float* __restrict__ cb) {
    const int bid = blockIdx.x;
    const int lane = threadIdx.x & 63, wv = threadIdx.x >> 6;
    if (bid == 384) {
        if (wv != 0) return;
        float s = 0.f;
#pragma unroll
        for (int m = 0; m < 12; m++) s += bq[lane + 64 * m] * bk[lane + 64 * m];
#pragma unroll
        for (int o = 1; o < 64; o <<= 1) s += __shfl_xor(s, o);
        if (lane == 0) cb[0] = s;
        return;
    }
    const bool isU = bid < 192;
    const int row = (isU ? bid : bid - 192) * 4 + wv;
    const float* W = isU ? wq : wk;
    const float* bvec = isU ? bk : bq;
    const float* wr = W + (size_t)row * DD;
    float s = 0.f;
#pragma unroll
    for (int m = 0; m < 12; m++) s += wr[lane + 64 * m] * bvec[lane + 64 * m];
#pragma unroll
    for (int o = 1; o < 64; o <<= 1) s += __shfl_xor(s, o);
    if (lane == 0) (isU ? u : v)[row] = s;
}

// ---------------- K2: LayerNorm + per-row bias dots (wave per row) ----------------
__global__ __launch_bounds__(256) void ln_kernel(const float* __restrict__ x,
        const float* __restrict__ lw, const float* __restrict__ lb,
        const float* __restrict__ u, const float* __restrict__ v,
        __bf16* __restrict__ h, float* __restrict__ Aarr, float* __restrict__ Barr) {
    const int row = blockIdx.x * 4 + (threadIdx.x >> 6);
    const int lane = threadIdx.x & 63;
    const float* xr = x + (size_t)row * DD + lane * 12;
    f32x4 a0 = *(const f32x4*)(xr), a1 = *(const f32x4*)(xr + 4), a2 = *(const f32x4*)(xr + 8);
    float xs[12];
#pragma unroll
    for (int c = 0; c < 4; c++) { xs[c] = a0[c]; xs[4 + c] = a1[c]; xs[8 + c] = a2[c]; }
    float s = 0.f, ss = 0.f;
#pragma unroll
    for (int c = 0; c < 12; c++) { s += xs[c]; ss += xs[c] * xs[c]; }
#pragma unroll
    for (int o = 1; o < 64; o <<= 1) { s += __shfl_xor(s, o); ss += __shfl_xor(ss, o); }
    const float mu = s * (1.0f / DD);
    const float var = ss * (1.0f / DD) - mu * mu;
    const float rstd = 1.0f / sqrtf(var + 1e-12f);
    const float* wp = lw + lane * 12; const float* bp = lb + lane * 12;
    const float* up = u + lane * 12;  const float* vp = v + lane * 12;
    f32x4 w0 = *(const f32x4*)(wp), w1 = *(const f32x4*)(wp + 4), w2 = *(const f32x4*)(wp + 8);
    f32x4 b0 = *(const f32x4*)(bp), b1 = *(const f32x4*)(bp + 4), b2 = *(const f32x4*)(bp + 8);
    f32x4 u0 = *(const f32x4*)(up), u1 = *(const f32x4*)(up + 4), u2 = *(const f32x4*)(up + 8);
    f32x4 v0 = *(const f32x4*)(vp), v1 = *(const f32x4*)(vp + 4), v2 = *(const f32x4*)(vp + 8);
    float wv[12], bv[12], uv[12], vv[12];
#pragma unroll
    for (int c = 0; c < 4; c++) {
        wv[c] = w0[c]; wv[4 + c] = w1[c]; wv[8 + c] = w2[c];
        bv[c] = b0[c]; bv[4 + c] = b1[c]; bv[8 + c] = b2[c];
        uv[c] = u0[c]; uv[4 + c] = u1[c]; uv[8 + c] = u2[c];
        vv[c] = v0[c]; vv[4 + c] = v1[c]; vv[8 + c] = v2[c];
    }
    bf16x4 o0, o1, o2;
    float ap = 0.f, bpv = 0.f;
#pragma unroll
    for (int c = 0; c < 12; c++) {
        const float y = (xs[c] - mu) * rstd * wv[c] + bv[c];
        ap += y * uv[c]; bpv += y * vv[c];
        if (c < 4) o0[c] = (__bf16)y; else if (c < 8) o1[c - 4] = (__bf16)y; else o2[c - 8] = (__bf16)y;
    }
    __bf16* hr = h + (size_t)row * DD + lane * 12;
    *(bf16x4*)(hr) = o0; *(bf16x4*)(hr + 4) = o1; *(bf16x4*)(hr + 8) = o2;
#pragma unroll
    for (int o = 1; o < 64; o <<= 1) { ap += __shfl_xor(ap, o); bpv += __shfl_xor(bpv, o); }
    if (lane == 0) { Aarr[row] = ap; Barr[row] = bpv; }
}

// ---------------- K3: GEMM C[M,768] = A[M,768] @ Bt[768,768]^T (bf16 out) ----------------
// 128x128 tile, 4 waves (2x2 of 64x64), BK=32, mfma_f32_16x16x32_bf16,
// global_load_lds width 16, Bt row-major [n][k].
__global__ __launch_bounds__(256) void gemm768_kernel(const __bf16* __restrict__ A,
        const __bf16* __restrict__ Bt, __bf16* __restrict__ C) {
    __shared__ __attribute__((aligned(16))) __bf16 As[128][32];
    __shared__ __attribute__((aligned(16))) __bf16 Bs[128][32];
    const int m0 = blockIdx.x * 128;
    const int n0 = blockIdx.y * 128;
    const int t = threadIdx.x;
    const int wave = t >> 6, lane = t & 63;
    const int wr = wave >> 1, wc = wave & 1;
    f32x4 acc[4][4] = {};

    char* asb = (char*)&As[0][0];
    char* bsb = (char*)&Bs[0][0];
    const int c0  = wave * 64 + lane;        // 16B chunk id, issue 0
    const int rA0 = c0 >> 2;                 // tile row (4 chunks per 64B row)
    const int cA0 = (c0 & 3) << 3;           // k-element offset within row

    for (int k0 = 0; k0 < DD; k0 += 32) {
        const __bf16* ga0 = A  + (size_t)(m0 + rA0) * DD + k0 + cA0;
        const __bf16* ga1 = ga0 + (size_t)64 * DD;
        const __bf16* gb0 = Bt + (size_t)(n0 + rA0) * DD + k0 + cA0;
        const __bf16* gb1 = gb0 + (size_t)64 * DD;
        __builtin_amdgcn_global_load_lds((const AS1 void*)(ga0), (AS3 void*)(asb + wave * 1024),        16, 0, 0);
        __builtin_amdgcn_global_load_lds((const AS1 void*)(ga1), (AS3 void*)(asb + 4096 + wave * 1024), 16, 0, 0);
        __builtin_amdgcn_global_load_lds((const AS1 void*)(gb0), (AS3 void*)(bsb + wave * 1024),        16, 0, 0);
        __builtin_amdgcn_global_load_lds((const AS1 void*)(gb1), (AS3 void*)(bsb + 4096 + wave * 1024), 16, 0, 0);
        __syncthreads();
        const int r = lane & 15, ko = (lane >> 4) << 3;
        bf16x8 af[4], bvf[4];
#pragma unroll
        for (int i = 0; i < 4; i++) af[i]  = *(const bf16x8*)&As[wr * 64 + i * 16 + r][ko];
#pragma unroll
        for (int j = 0; j < 4; j++) bvf[j] = *(const bf16x8*)&Bs[wc * 64 + j * 16 + r][ko];
#pragma unroll
        for (int i = 0; i < 4; i++)
#pragma unroll
            for (int j = 0; j < 4; j++)
                acc[i][j] = __builtin_amdgcn_mfma_f32_16x16x32_bf16(af[i], bvf[j], acc[i][j], 0, 0, 0);
        __syncthreads();
    }
    // epilogue: col=lane&15, row=(lane>>4)*4+rr (m89-verified layout)
#pragma unroll
    for (int i = 0; i < 4; i++) {
        const int mm = m0 + wr * 64 + i * 16 + (lane >> 4) * 4;
#pragma unroll
        for (int j = 0; j < 4; j++) {
            const int nn = n0 + wc * 64 + j * 16 + (lane & 15);
#pragma unroll
            for (int rr = 0; rr < 4; rr++)
                C[(size_t)(mm + rr) * DD + nn] = (__bf16)acc[i][j][rr];
        }
    }
}

// ---------------- K4: band dots h[s].R[s+-1] + 2-way softmax ----------------
__global__ __launch_bounds__(256) void band_kernel(const __bf16* __restrict__ h,
        const __bf16* __restrict__ R, const int* __restrict__ att,
        const float* __restrict__ Aarr, const float* __restrict__ Barr,
        const float* __restrict__ cbp, float* __restrict__ pu, float* __restrict__ pd) {
    const int idx  = blockIdx.x * 4 + (threadIdx.x >> 6);   // row 0..MM-1
    const int lane = threadIdx.x & 63;
    const int b = idx >> 11;
    const int s = idx & 2047;
    const __bf16* hp = h + (size_t)idx * DD + lane * 12;
    bf16x4 h0 = *(const bf16x4*)(hp), h1 = *(const bf16x4*)(hp + 4), h2 = *(const bf16x4*)(hp + 8);
    float hv[12];
#pragma unroll
    for (int c = 0; c < 4; c++) { hv[c] = (float)h0[c]; hv[4 + c] = (float)h1[c]; hv[8 + c] = (float)h2[c]; }
    float du = 0.f, dn = 0.f;
    if (s < SS - 1) {
        const __bf16* rp = R + (size_t)(idx + 1) * DD + lane * 12;
        bf16x4 r0 = *(const bf16x4*)(rp), r1 = *(const bf16x4*)(rp + 4), r2 = *(const bf16x4*)(rp + 8);
#pragma unroll
        for (int c = 0; c < 4; c++) {
            du += hv[c] * (float)r0[c];
            du += hv[4 + c] * (float)r1[c];
            du += hv[8 + c] * (float)r2[c];
        }
    }
    if (s > 0) {
        const __bf16* rp = R + (size_t)(idx - 1) * DD + lane * 12;
        bf16x4 r0 = *(const bf16x4*)(rp), r1 = *(const bf16x4*)(rp + 4), r2 = *(const bf16x4*)(rp + 8);
#pragma unroll
        for (int c = 0; c < 4; c++) {
            dn += hv[c] * (float)r0[c];
            dn += hv[4 + c] * (float)r1[c];
            dn += hv[8 + c] * (float)r2[c];
        }
    }
#pragma unroll
    for (int o = 1; o < 64; o <<= 1) { du += __shfl_xor(du, o); dn += __shfl_xor(dn, o); }
    if (lane == 0) {
        const float cb = cbp[0];
        const float As = Aarr[idx];
        const float eu = (du + As + ((s < SS - 1) ? Barr[idx + 1] : 0.f) + cb) * (1.0f / DD);
        const float ed = (dn + As + ((s > 0)      ? Barr[idx - 1] : 0.f) + cb) * (1.0f / DD);
        const bool au = (s < SS - 1) && ((att[((size_t)b * SS + s) * SS + (s + 1)] & 1) != 0);
        const bool ad = (s > 0)      && ((att[((size_t)b * SS + s) * SS + (s - 1)] & 1) != 0);
        float puv = 0.f, pdv = 0.f;
        if (au || ad) {
            float mx = au ? eu : ed;
            if (au && ad) mx = fmaxf(eu, ed);
            const float zu = au ? expf(eu - mx) : 0.f;
            const float zd = ad ? expf(ed - mx) : 0.f;
            const float iz = 1.f / (zu + zd);
            puv = zu * iz; pdv = zd * iz;
        }
        pu[idx] = puv; pd[idx] = pdv;
    }
}

// ---------------- K5: per-batch band n, log, double prefix scan ----------------
__global__ __launch_bounds__(256) void scan_kernel(const float* __restrict__ pu,
        const float* __restrict__ pd, const float* __restrict__ prior,
        float* __restrict__ nb, double* __restrict__ P) {
    const int b = blockIdx.x;
    const int t = threadIdx.x;
    double L[8];
    double mysum = 0.0;
#pragma unroll
    for (int e = 0; e < 8; e++) {
        const int s = t * 8 + e;
        double Lv = 0.0;
        float nbv = 0.f;
        if (s < SS - 1) {
            const float a = pu[b * SS + s];
            const float c = pd[b * SS + s + 1];
            nbv = sqrtf(a * c + 1e-9f);
            const float pr = prior[(size_t)b * SS * SS + (size_t)s * SS + s + 1];
            const float nsup = pr + (1.f - pr) * nbv;
            Lv = log((double)nsup + 1e-9);
        }
        nb[b * SS + s] = nbv;
        L[e] = Lv; mysum += Lv;
    }
    __shared__ double warr[256];
    warr[t] = mysum;
    __syncthreads();
    for (int o = 1; o < 256; o <<= 1) {
        double v = 0.0;
        if (t >= o) v = warr[t - o];
        __syncthreads();
        if (t >= o) warr[t] += v;
        __syncthreads();
    }
    double run = warr[t] - mysum;    // exclusive prefix across threads
#pragma unroll
    for (int e = 0; e < 8; e++) {
        P[(size_t)b * SS + t * 8 + e] = run;
        run += L[e];
    }
}

// ---------------- K6: fused elementwise output (g and n) ----------------
__global__ __launch_bounds__(256) void out_kernel(const float* __restrict__ prior,
        const float* __restrict__ nb, const double* __restrict__ P,
        float* __restrict__ gout, float* __restrict__ nout) {
    const size_t f = (size_t)blockIdx.x * 256 + threadIdx.x;   // float4 index
    const int b = (int)(f >> 20);            // SS*SS/4 = 2^20
    const size_t r = f & 1048575;
    const int i  = (int)(r >> 9);            // SS/4 = 512 float4 per row
    const int k4 = (int)(r & 511) * 4;
    const f32x4 pv = *(const f32x4*)(prior + (f << 2));
    const double Pi = P[(size_t)b * SS + i];
    f32x4 nres, gres;
#pragma unroll
    for (int c = 0; c < 4; c++) {
        const int k = k4 + c;
        const float pr = pv[c];
        float v = 3.16227766016838e-5f;      // sqrt(1e-9)
        if (k == i + 1)      v = nb[b * SS + i];
        else if (k == i - 1) v = nb[b * SS + k];
        const float nval = pr + (1.f - pr) * v;
        nres[c] = nval;
        float g;
        if (k == i) {
            g = nval;                        // diagonal: diag_part = n[i,i]
        } else {
            const double Pk = P[(size_t)b * SS + k];
            const double dd = (k > i) ? (Pk - Pi) : (Pi - Pk);
            g = expf((float)dd) + 1e-9f;
        }
        gres[c] = g;
    }
    *(f32x4*)(gout + (f << 2)) = gres;
    *(f32x4*)(nout + (f << 2)) = nres;
}

extern "C" void kernel_launch(void* const* d_in, const int* in_sizes, int n_in,
                              void* d_out, int out_size, void* d_ws, size_t ws_size,
                              hipStream_t stream) {
    const float* hs    = (const float*)d_in[0];
    const int*   att   = (const int*)d_in[1];
    const float* prior = (const float*)d_in[2];
    const float* ln_w  = (const float*)d_in[3];
    const float* ln_b  = (const float*)d_in[4];
    const float* wq    = (const float*)d_in[5];
    const float* bq    = (const float*)d_in[6];
    const float* wk    = (const float*)d_in[7];
    const float* bk    = (const float*)d_in[8];

    float* gout = (float*)d_out;                       // g first (return order)
    float* nout = gout + (size_t)BB * SS * SS;

    char* ws = (char*)d_ws;
    __bf16* h    = (__bf16*)(ws);                      // 12,582,912
    __bf16* Wqb  = (__bf16*)(ws + 12582912);           //  1,179,648
    __bf16* Wkb  = (__bf16*)(ws + 13762560);           //  1,179,648
    __bf16* G    = (__bf16*)(ws + 14942208);           //  1,179,648
    __bf16* R    = (__bf16*)(ws + 16121856);           // 12,582,912
    float*  u    = (float*) (ws + 28704768);           //      3,072
    float*  v    = (float*) (ws + 28707840);           //      3,072
    float*  Aarr = (float*) (ws + 28710912);           //     32,768
    float*  Barr = (float*) (ws + 28743680);           //     32,768
    float*  cb   = (float*) (ws + 28776448);           //        256
    float*  pu   = (float*) (ws + 28776704);           //     32,768
    float*  pd   = (float*) (ws + 28809472);           //     32,768
    float*  nbuf = (float*) (ws + 28842240);           //     32,768
    double* P    = (double*)(ws + 28875008);           //     65,536

    wcvt_kernel<<<dim3(1152), dim3(256), 0, stream>>>(wq, wk, Wqb, Wkb);
    uvcb_kernel<<<dim3(385), dim3(256), 0, stream>>>(wq, wk, bq, bk, u, v, cb);
    ln_kernel<<<dim3(MM / 4), dim3(256), 0, stream>>>(hs, ln_w, ln_b, u, v, h, Aarr, Barr);
    gemm768_kernel<<<dim3(6, 6), dim3(256), 0, stream>>>(Wqb, Wkb, G);       // G = Wq @ Wk^T
    gemm768_kernel<<<dim3(MM / 128, 6), dim3(256), 0, stream>>>(h, G, R);    // R = h @ G^T
    band_kernel<<<dim3(MM / 4), dim3(256), 0, stream>>>(h, R, att, Aarr, Barr, cb, pu, pd);
    scan_kernel<<<dim3(BB), dim3(256), 0, stream>>>(pu, pd, prior, nbuf, P);
    out_kernel<<<dim3((BB * SS * SS / 4) / 256), dim3(256), 0, stream>>>(prior, nbuf, P, gout, nout);
}